// Round 4
// baseline (413.653 us; speedup 1.0000x reference)
//
#include <hip/hip_runtime.h>
#include <hip/hip_bf16.h>
#include <stdint.h>

#define BATCH 4
#define SEQ   2048
#define EMB   1024
#define NHEAD 16
#define HDIM  64

typedef __bf16 bf16x8 __attribute__((ext_vector_type(8)));
typedef float  f32x4  __attribute__((ext_vector_type(4)));
typedef float  f32x16 __attribute__((ext_vector_type(16)));

// ---------------- fp32 -> bf16 cast, 4 elems/thread ----------------
__global__ __launch_bounds__(256) void cvt_f32_bf16(const float* __restrict__ in,
                                                    __bf16* __restrict__ out, int n4) {
  int i = blockIdx.x * 256 + threadIdx.x;
  if (i >= n4) return;
  float4 v = reinterpret_cast<const float4*>(in)[i];
  union { ushort4 u; __bf16 b[4]; } o;
  o.b[0] = (__bf16)v.x; o.b[1] = (__bf16)v.y;
  o.b[2] = (__bf16)v.z; o.b[3] = (__bf16)v.w;
  reinterpret_cast<ushort4*>(out)[i] = o.u;
}

__device__ __forceinline__ void gload_lds16(const void* g, void* l) {
  __builtin_amdgcn_global_load_lds((const uint32_t __attribute__((address_space(1)))*)g,
                                   (uint32_t __attribute__((address_space(3)))*)l, 16, 0, 0);
}

// ---------------- GEMM v2: 2-phase dbuf, 256x128 tile, BK=64 ----------------
// C = A(MxK) * Bt(NxK)^T + bias. 512 threads = 8 waves (4x2), wave tile 64x64.
// LDS 96KB: As[2][256][64], Bs[2][128][64] bf16, XOR-swizzled (row&7)<<4.
enum { EPI_BF16 = 0, EPI_F32 = 1, EPI_VT = 2 };

template <int MODE>
__global__ __launch_bounds__(512, 2)
void gemm2(const __bf16* __restrict__ A, const __bf16* __restrict__ Bt,
           const float* __restrict__ bias, void* __restrict__ Cout,
           int M, int N, int K) {
  __shared__ __bf16 As[2][256 * 64];
  __shared__ __bf16 Bs[2][128 * 64];

  const int tid  = threadIdx.x;
  const int wave = tid >> 6, lane = tid & 63;
  const int l4 = lane >> 4, l15 = lane & 15;
  const int row0 = blockIdx.x * 256, col0 = blockIdx.y * 128;
  const int wr = (wave >> 1) * 64, wc = (wave & 1) * 64;

  // staging: thread covers LDS row sr=tid>>3, byte col (tid&7)*16 (chunk-strided by 64 rows)
  const int sr = tid >> 3;
  const int scb = ((tid & 7) * 16) ^ ((sr & 7) << 4);   // pre-swizzled source byte col
  const char* gA = (const char*)A  + ((size_t)(row0 + sr) * K) * 2 + scb;
  const char* gB = (const char*)Bt + ((size_t)(col0 + sr) * K) * 2 + scb;
  const size_t rstride = (size_t)64 * K * 2;            // 64 rows of global

  f32x4 acc[4][4] = {};

  auto STAGE = [&](int bi, int t) {
    char* lA = (char*)&As[bi][0] + wave * 1024;
    char* lB = (char*)&Bs[bi][0] + wave * 1024;
    const size_t ko = (size_t)t * 128;
#pragma unroll
    for (int c = 0; c < 4; ++c)
      gload_lds16(gA + ko + c * rstride, lA + c * 8192);
#pragma unroll
    for (int c = 0; c < 2; ++c)
      gload_lds16(gB + ko + c * rstride, lB + c * 8192);
  };

  const int NT = K >> 6;
  STAGE(0, 0);
  asm volatile("s_waitcnt vmcnt(0)" ::: "memory");
  __builtin_amdgcn_s_barrier();
  __builtin_amdgcn_sched_barrier(0);

  const int swz = (l15 & 7) << 4;
  int cur = 0;
  for (int t = 0; t < NT; ++t) {
    if (t + 1 < NT) STAGE(cur ^ 1, t + 1);

    const char* la = (const char*)&As[cur][0];
    const char* lb = (const char*)&Bs[cur][0];
    bf16x8 af[4][2], bfv[4][2];
#pragma unroll
    for (int m = 0; m < 4; ++m)
#pragma unroll
      for (int k = 0; k < 2; ++k)
        af[m][k] = *(const bf16x8*)(la + (wr + m * 16 + l15) * 128 + ((k * 64 + l4 * 16) ^ swz));
#pragma unroll
    for (int n = 0; n < 4; ++n)
#pragma unroll
      for (int k = 0; k < 2; ++k)
        bfv[n][k] = *(const bf16x8*)(lb + (wc + n * 16 + l15) * 128 + ((k * 64 + l4 * 16) ^ swz));

    asm volatile("s_waitcnt lgkmcnt(0)" ::: "memory");
    __builtin_amdgcn_sched_barrier(0);
    __builtin_amdgcn_s_setprio(1);
#pragma unroll
    for (int k = 0; k < 2; ++k)
#pragma unroll
      for (int m = 0; m < 4; ++m)
#pragma unroll
        for (int n = 0; n < 4; ++n)
          acc[m][n] = __builtin_amdgcn_mfma_f32_16x16x32_bf16(af[m][k], bfv[n][k], acc[m][n], 0, 0, 0);
    __builtin_amdgcn_s_setprio(0);

    asm volatile("s_waitcnt vmcnt(0)" ::: "memory");
    __builtin_amdgcn_s_barrier();
    __builtin_amdgcn_sched_barrier(0);
    cur ^= 1;
  }

  // epilogue: D elem (row=l4*4+i, col=l15) per 16x16 frag
#pragma unroll
  for (int m = 0; m < 4; ++m) {
    const int r = row0 + wr + m * 16 + l4 * 4;
#pragma unroll
    for (int n = 0; n < 4; ++n) {
      const int c  = col0 + wc + n * 16 + l15;
      const float bb = bias[c];
      if (MODE == EPI_F32) {
        float* C = (float*)Cout;
#pragma unroll
        for (int i = 0; i < 4; ++i) C[(size_t)(r + i) * N + c] = acc[m][n][i] + bb;
      } else if (MODE == EPI_BF16) {
        __bf16* C = (__bf16*)Cout;
#pragma unroll
        for (int i = 0; i < 4; ++i) C[(size_t)(r + i) * N + c] = (__bf16)(acc[m][n][i] + bb);
      } else {  // EPI_VT: write V^T as [b][h][d][s]
        const int b = r >> 11, s = r & (SEQ - 1);
        const int h = c >> 6, d = c & (HDIM - 1);
        union { ushort4 u; __bf16 x[4]; } o;
#pragma unroll
        for (int i = 0; i < 4; ++i) o.x[i] = (__bf16)(acc[m][n][i] + bb);
        *(ushort4*)((__bf16*)Cout + ((size_t)((b * NHEAD + h) * HDIM + d)) * SEQ + s) = o.u;
      }
    }
  }
}

// ---------------- flash attention v2: swapped-QK^T, 32x32 MFMA ----------------
// grid (B*H=64, SEQ/256=8), 512 threads (8 waves x 32 q-rows).
__device__ __forceinline__ f32x16 mfma32(bf16x8 a, bf16x8 b, f32x16 c) {
  return __builtin_amdgcn_mfma_f32_32x32x16_bf16(a, b, c, 0, 0, 0);
}

__global__ __launch_bounds__(512, 2)
void attn_fwd2(const __bf16* __restrict__ Q, const __bf16* __restrict__ Kk,
               const __bf16* __restrict__ Vt, __bf16* __restrict__ O) {
  __shared__ __bf16 Ks[2][64 * 64];   // [key][d], XOR-swizzled rows
  __shared__ __bf16 Vs[2][64 * 64];   // [d][key], XOR-swizzled rows

  const int tid = threadIdx.x;
  const int w = tid >> 6, lane = tid & 63;
  const int l31 = lane & 31, hi = lane >> 5;
  const int bh = blockIdx.x, b = bh >> 4, h = bh & 15;
  const int q0 = blockIdx.y * 256 + w * 32;

  // Q fragments (B-operand), prescaled by (1/8)*log2(e) for exp2-domain softmax
  bf16x8 qf[4];
  {
    const __bf16* qb = Q + (size_t)(b * SEQ + q0 + l31) * EMB + h * HDIM + hi * 8;
#pragma unroll
    for (int ks = 0; ks < 4; ++ks) {
      bf16x8 t = *(const bf16x8*)(qb + ks * 16);
#pragma unroll
      for (int j = 0; j < 8; ++j) t[j] = (__bf16)((float)t[j] * 0.1803368801111244f);
      qf[ks] = t;
    }
  }

  const int srow = w * 8 + (lane >> 3);
  const int sswz = ((lane & 7) * 16) ^ ((srow & 7) << 4);
  const char* kg = (const char*)(Kk + (size_t)(b * SEQ) * EMB + h * HDIM)
                   + (size_t)srow * (EMB * 2) + sswz;
  const char* vg = (const char*)(Vt + (size_t)((b * NHEAD + h) * HDIM) * SEQ)
                   + (size_t)srow * (SEQ * 2) + sswz;

  auto STAGE = [&](int bi, int t) {
    gload_lds16(kg + (size_t)t * (64 * EMB * 2), (char*)&Ks[bi][0] + w * 1024);
    gload_lds16(vg + (size_t)t * 128,            (char*)&Vs[bi][0] + w * 1024);
  };

  f32x16 oacc0 = {}, oacc1 = {};
  float mx = -1e30f, ls = 0.f;
  const int rswz = (l31 & 7) << 4;

  STAGE(0, 0);
  for (int t = 0; t < 32; ++t) {
    const int bi = t & 1;
    if (t < 31) {
      STAGE(bi ^ 1, t + 1);
      asm volatile("s_waitcnt vmcnt(2)" ::: "memory");
    } else {
      asm volatile("s_waitcnt vmcnt(0)" ::: "memory");
    }
    __builtin_amdgcn_s_barrier();
    __builtin_amdgcn_sched_barrier(0);

    // QK^T (swapped): S^T[key][q]
    f32x16 sc0 = {}, sc1 = {};
    const char* kb = (const char*)&Ks[bi][0];
#pragma unroll
    for (int ks = 0; ks < 4; ++ks) {
      const int o = (ks * 32 + hi * 16) ^ rswz;
      bf16x8 k0 = *(const bf16x8*)(kb + l31 * 128 + o);
      bf16x8 k1 = *(const bf16x8*)(kb + (l31 + 32) * 128 + o);
      sc0 = mfma32(k0, qf[ks], sc0);
      sc1 = mfma32(k1, qf[ks], sc1);
    }

    // online softmax in exp2 domain, per-lane row q
    float pm = sc0[0];
#pragma unroll
    for (int r = 1; r < 16; ++r) pm = fmaxf(pm, sc0[r]);
#pragma unroll
    for (int r = 0; r < 16; ++r) pm = fmaxf(pm, sc1[r]);
    pm = fmaxf(pm, __shfl_xor(pm, 32));
    const float mn = fmaxf(mx, pm);
    const float corr = exp2f(mx - mn);
    mx = mn;
    float rs = 0.f;
#pragma unroll
    for (int r = 0; r < 16; ++r) { sc0[r] = exp2f(sc0[r] - mn); rs += sc0[r]; }
#pragma unroll
    for (int r = 0; r < 16; ++r) { sc1[r] = exp2f(sc1[r] - mn); rs += sc1[r]; }
    rs += __shfl_xor(rs, 32);
    ls = ls * corr + rs;
#pragma unroll
    for (int r = 0; r < 16; ++r) { oacc0[r] *= corr; oacc1[r] *= corr; }

    // P -> bf16 A-frags (P^T B-operand): pack pairs + lane^32 exchange
    union Fu { uint32_t w[4]; bf16x8 v; };
    auto pk = [](float a, float b) -> uint32_t {
      union { __bf16 h[2]; uint32_t u; } z;
      z.h[0] = (__bf16)a; z.h[1] = (__bf16)b; return z.u;
    };
    bf16x8 pa[4];
    {
      uint32_t A0 = pk(sc0[0], sc0[1]),  A1 = pk(sc0[2], sc0[3]);
      uint32_t B0 = pk(sc0[4], sc0[5]),  B1 = pk(sc0[6], sc0[7]);
      uint32_t C0 = pk(sc0[8], sc0[9]),  C1 = pk(sc0[10], sc0[11]);
      uint32_t D0 = pk(sc0[12], sc0[13]), D1 = pk(sc0[14], sc0[15]);
      uint32_t sA0 = __shfl_xor((int)A0, 32), sA1 = __shfl_xor((int)A1, 32);
      uint32_t sB0 = __shfl_xor((int)B0, 32), sB1 = __shfl_xor((int)B1, 32);
      uint32_t sC0 = __shfl_xor((int)C0, 32), sC1 = __shfl_xor((int)C1, 32);
      uint32_t sD0 = __shfl_xor((int)D0, 32), sD1 = __shfl_xor((int)D1, 32);
      Fu f0, f1;
      f0.w[0] = hi ? sB0 : A0;  f0.w[1] = hi ? sB1 : A1;
      f0.w[2] = hi ? B0 : sA0;  f0.w[3] = hi ? B1 : sA1;
      f1.w[0] = hi ? sD0 : C0;  f1.w[1] = hi ? sD1 : C1;
      f1.w[2] = hi ? D0 : sC0;  f1.w[3] = hi ? D1 : sC1;
      pa[0] = f0.v; pa[1] = f1.v;
      uint32_t E0 = pk(sc1[0], sc1[1]),  E1 = pk(sc1[2], sc1[3]);
      uint32_t F0 = pk(sc1[4], sc1[5]),  F1 = pk(sc1[6], sc1[7]);
      uint32_t G0 = pk(sc1[8], sc1[9]),  G1 = pk(sc1[10], sc1[11]);
      uint32_t H0 = pk(sc1[12], sc1[13]), H1 = pk(sc1[14], sc1[15]);
      uint32_t sE0 = __shfl_xor((int)E0, 32), sE1 = __shfl_xor((int)E1, 32);
      uint32_t sF0 = __shfl_xor((int)F0, 32), sF1 = __shfl_xor((int)F1, 32);
      uint32_t sG0 = __shfl_xor((int)G0, 32), sG1 = __shfl_xor((int)G1, 32);
      uint32_t sH0 = __shfl_xor((int)H0, 32), sH1 = __shfl_xor((int)H1, 32);
      Fu f2, f3;
      f2.w[0] = hi ? sF0 : E0;  f2.w[1] = hi ? sF1 : E1;
      f2.w[2] = hi ? F0 : sE0;  f2.w[3] = hi ? F1 : sE1;
      f3.w[0] = hi ? sH0 : G0;  f3.w[1] = hi ? sH1 : G1;
      f3.w[2] = hi ? H0 : sG0;  f3.w[3] = hi ? H1 : sG1;
      pa[2] = f2.v; pa[3] = f3.v;
    }

    // PV (swapped): O^T += Vt_tile . P^T
    const char* vb = (const char*)&Vs[bi][0];
#pragma unroll
    for (int ks = 0; ks < 4; ++ks) {
      const int o = (ks * 32 + hi * 16) ^ rswz;
      bf16x8 v0 = *(const bf16x8*)(vb + l31 * 128 + o);
      bf16x8 v1 = *(const bf16x8*)(vb + (l31 + 32) * 128 + o);
      oacc0 = mfma32(v0, pa[ks], oacc0);
      oacc1 = mfma32(v1, pa[ks], oacc1);
    }

    __builtin_amdgcn_s_barrier();
    __builtin_amdgcn_sched_barrier(0);
  }

  const float inv = 1.f / ls;
  __bf16* ob = O + (size_t)(b * SEQ + q0 + l31) * EMB + h * HDIM;
#pragma unroll
  for (int c = 0; c < 4; ++c) {
    union { ushort4 u; __bf16 x[4]; } o0, o1;
#pragma unroll
    for (int i = 0; i < 4; ++i) {
      o0.x[i] = (__bf16)(oacc0[4 * c + i] * inv);
      o1.x[i] = (__bf16)(oacc1[4 * c + i] * inv);
    }
    *(ushort4*)(ob + 8 * c + 4 * hi)      = o0.u;
    *(ushort4*)(ob + 32 + 8 * c + 4 * hi) = o1.u;
  }
}

// ---------------- launch ----------------
extern "C" void kernel_launch(void* const* d_in, const int* in_sizes, int n_in,
                              void* d_out, int out_size, void* d_ws, size_t ws_size,
                              hipStream_t stream) {
  const float* query = (const float*)d_in[0];
  const float* key   = (const float*)d_in[1];
  const float* value = (const float*)d_in[2];
  const float* Wq = (const float*)d_in[3]; const float* bq = (const float*)d_in[4];
  const float* Wk = (const float*)d_in[5]; const float* bk = (const float*)d_in[6];
  const float* Wv = (const float*)d_in[7]; const float* bv = (const float*)d_in[8];
  const float* Wo = (const float*)d_in[9]; const float* bo = (const float*)d_in[10];

  char* ws = (char*)d_ws;
  const size_t MB = 1u << 20;
  __bf16* Xb  = (__bf16*)(ws);             // 16 MB staging (also reused for attn out)
  __bf16* Qb  = (__bf16*)(ws + 16 * MB);
  __bf16* Kb  = (__bf16*)(ws + 32 * MB);
  __bf16* Vt  = (__bf16*)(ws + 48 * MB);
  __bf16* Wqb = (__bf16*)(ws + 64 * MB);
  __bf16* Wkb = (__bf16*)(ws + 66 * MB);
  __bf16* Wvb = (__bf16*)(ws + 68 * MB);
  __bf16* Wob = (__bf16*)(ws + 70 * MB);

  const int NE = BATCH * SEQ * EMB;
  const int NW = EMB * EMB;
  const int M = BATCH * SEQ;

  dim3 blk(256);
  dim3 gg(M / 256, EMB / 128);
  dim3 gblk(512);

  cvt_f32_bf16<<<dim3(NW / 4 / 256), blk, 0, stream>>>(Wq, Wqb, NW / 4);
  cvt_f32_bf16<<<dim3(NW / 4 / 256), blk, 0, stream>>>(Wk, Wkb, NW / 4);
  cvt_f32_bf16<<<dim3(NW / 4 / 256), blk, 0, stream>>>(Wv, Wvb, NW / 4);
  cvt_f32_bf16<<<dim3(NW / 4 / 256), blk, 0, stream>>>(Wo, Wob, NW / 4);

  cvt_f32_bf16<<<dim3(NE / 4 / 256), blk, 0, stream>>>(query, Xb, NE / 4);
  gemm2<EPI_BF16><<<gg, gblk, 0, stream>>>(Xb, Wqb, bq, Qb, M, EMB, EMB);
  cvt_f32_bf16<<<dim3(NE / 4 / 256), blk, 0, stream>>>(key, Xb, NE / 4);
  gemm2<EPI_BF16><<<gg, gblk, 0, stream>>>(Xb, Wkb, bk, Kb, M, EMB, EMB);
  cvt_f32_bf16<<<dim3(NE / 4 / 256), blk, 0, stream>>>(value, Xb, NE / 4);
  gemm2<EPI_VT><<<gg, gblk, 0, stream>>>(Xb, Wvb, bv, Vt, M, EMB, EMB);

  attn_fwd2<<<dim3(BATCH * NHEAD, SEQ / 256), gblk, 0, stream>>>(Qb, Kb, Vt, Xb);

  gemm2<EPI_F32><<<gg, gblk, 0, stream>>>(Xb, Wob, bo, d_out, M, EMB, EMB);
}

// Round 5
// 379.524 us; speedup vs baseline: 1.0899x; 1.0899x over previous
//
#include <hip/hip_runtime.h>
#include <hip/hip_bf16.h>
#include <stdint.h>

#define BATCH 4
#define SEQ   2048
#define EMB   1024
#define NHEAD 16
#define HDIM  64

typedef __bf16 bf16x8 __attribute__((ext_vector_type(8)));
typedef float  f32x4  __attribute__((ext_vector_type(4)));
typedef float  f32x16 __attribute__((ext_vector_type(16)));

extern "C" __device__ float __ocml_native_exp2_f32(float);  // raw v_exp_f32

// ---------------- fp32 -> bf16 cast, 4 elems/thread ----------------
__global__ __launch_bounds__(256) void cvt_f32_bf16(const float* __restrict__ in,
                                                    __bf16* __restrict__ out, int n4) {
  int i = blockIdx.x * 256 + threadIdx.x;
  if (i >= n4) return;
  float4 v = reinterpret_cast<const float4*>(in)[i];
  union { ushort4 u; __bf16 b[4]; } o;
  o.b[0] = (__bf16)v.x; o.b[1] = (__bf16)v.y;
  o.b[2] = (__bf16)v.z; o.b[3] = (__bf16)v.w;
  reinterpret_cast<ushort4*>(out)[i] = o.u;
}

__device__ __forceinline__ void gload_lds16(const void* g, void* l) {
  __builtin_amdgcn_global_load_lds((const uint32_t __attribute__((address_space(1)))*)g,
                                   (uint32_t __attribute__((address_space(3)))*)l, 16, 0, 0);
}

// ---------------- GEMM v3: 3-buffer, prefetch-distance-2, counted vmcnt ----------------
// C = A(MxK) * Bt(NxK)^T + bias. 512 threads = 8 waves (4x2), wave tile 64x64, BK=64.
// LDS 144KB: As[3][256][64], Bs[3][128][64] bf16, XOR-swizzled (row&7)<<4 both sides.
enum { EPI_BF16 = 0, EPI_F32 = 1, EPI_VT = 2 };

template <int MODE>
__global__ __launch_bounds__(512)
void gemm3(const __bf16* __restrict__ A, const __bf16* __restrict__ Bt,
           const float* __restrict__ bias, void* __restrict__ Cout,
           int M, int N, int K) {
  __shared__ __bf16 As[3][256 * 64];
  __shared__ __bf16 Bs[3][128 * 64];

  const int tid  = threadIdx.x;
  const int wave = tid >> 6, lane = tid & 63;
  const int l4 = lane >> 4, l15 = lane & 15;
  const int row0 = blockIdx.x * 256, col0 = blockIdx.y * 128;
  const int wr = (wave >> 1) * 64, wc = (wave & 1) * 64;

  // staging: thread covers LDS row sr=tid>>3, byte col (tid&7)*16 (chunk-strided by 64 rows)
  const int sr = tid >> 3;
  const int scb = ((tid & 7) * 16) ^ ((sr & 7) << 4);   // pre-swizzled source byte col
  const char* gA = (const char*)A  + ((size_t)(row0 + sr) * K) * 2 + scb;
  const char* gB = (const char*)Bt + ((size_t)(col0 + sr) * K) * 2 + scb;
  const size_t rstride = (size_t)64 * K * 2;            // 64 rows of global

  f32x4 acc[4][4] = {};

  auto STAGE = [&](int bi, int t) {            // 6 gload_lds16 per thread
    char* lA = (char*)&As[bi][0] + wave * 1024;
    char* lB = (char*)&Bs[bi][0] + wave * 1024;
    const size_t ko = (size_t)t * 128;
#pragma unroll
    for (int c = 0; c < 4; ++c)
      gload_lds16(gA + ko + c * rstride, lA + c * 8192);
#pragma unroll
    for (int c = 0; c < 2; ++c)
      gload_lds16(gB + ko + c * rstride, lB + c * 8192);
  };

  const int NT = K >> 6;                       // 16 K-tiles
  STAGE(0, 0);
  STAGE(1, 1);

  const int swz = (l15 & 7) << 4;
  int cur = 0;
  for (int t = 0; t < NT; ++t) {
    // prefetch distance 2; own loads for buf[cur] complete once <=12 remain in flight
    if (t + 2 < NT) {
      int nb = cur + 2; if (nb >= 3) nb -= 3;
      STAGE(nb, t + 2);
      asm volatile("s_waitcnt vmcnt(12)" ::: "memory");
    } else if (t + 1 < NT) {
      asm volatile("s_waitcnt vmcnt(6)" ::: "memory");
    } else {
      asm volatile("s_waitcnt vmcnt(0)" ::: "memory");
    }
    __builtin_amdgcn_s_barrier();              // all waves' buf[cur] loads landed
    __builtin_amdgcn_sched_barrier(0);

    const char* la = (const char*)&As[cur][0];
    const char* lb = (const char*)&Bs[cur][0];
    bf16x8 af[4][2], bfv[4][2];
#pragma unroll
    for (int m = 0; m < 4; ++m)
#pragma unroll
      for (int k = 0; k < 2; ++k)
        af[m][k] = *(const bf16x8*)(la + (wr + m * 16 + l15) * 128 + ((k * 64 + l4 * 16) ^ swz));
#pragma unroll
    for (int n = 0; n < 4; ++n)
#pragma unroll
      for (int k = 0; k < 2; ++k)
        bfv[n][k] = *(const bf16x8*)(lb + (wc + n * 16 + l15) * 128 + ((k * 64 + l4 * 16) ^ swz));

    asm volatile("s_waitcnt lgkmcnt(0)" ::: "memory");
    __builtin_amdgcn_sched_barrier(0);
    __builtin_amdgcn_s_setprio(1);
#pragma unroll
    for (int k = 0; k < 2; ++k)
#pragma unroll
      for (int m = 0; m < 4; ++m)
#pragma unroll
        for (int n = 0; n < 4; ++n)
          acc[m][n] = __builtin_amdgcn_mfma_f32_16x16x32_bf16(af[m][k], bfv[n][k], acc[m][n], 0, 0, 0);
    __builtin_amdgcn_s_setprio(0);

    __builtin_amdgcn_s_barrier();              // reads done before buf[cur] is restaged
    __builtin_amdgcn_sched_barrier(0);
    ++cur; if (cur >= 3) cur = 0;
  }

  // epilogue: D elem (row=l4*4+i, col=l15) per 16x16 frag
#pragma unroll
  for (int m = 0; m < 4; ++m) {
    const int r = row0 + wr + m * 16 + l4 * 4;
#pragma unroll
    for (int n = 0; n < 4; ++n) {
      const int c  = col0 + wc + n * 16 + l15;
      const float bb = bias[c];
      if (MODE == EPI_F32) {
        float* C = (float*)Cout;
#pragma unroll
        for (int i = 0; i < 4; ++i) C[(size_t)(r + i) * N + c] = acc[m][n][i] + bb;
      } else if (MODE == EPI_BF16) {
        __bf16* C = (__bf16*)Cout;
#pragma unroll
        for (int i = 0; i < 4; ++i) C[(size_t)(r + i) * N + c] = (__bf16)(acc[m][n][i] + bb);
      } else {  // EPI_VT: write V^T as [b][h][d][s]
        const int b = r >> 11, s = r & (SEQ - 1);
        const int h = c >> 6, d = c & (HDIM - 1);
        union { ushort4 u; __bf16 x[4]; } o;
#pragma unroll
        for (int i = 0; i < 4; ++i) o.x[i] = (__bf16)(acc[m][n][i] + bb);
        *(ushort4*)((__bf16*)Cout + ((size_t)((b * NHEAD + h) * HDIM + d)) * SEQ + s) = o.u;
      }
    }
  }
}

// ---------------- flash attention v2: swapped-QK^T, 32x32 MFMA ----------------
// grid (B*H=64, SEQ/256=8), 512 threads (8 waves x 32 q-rows).
__device__ __forceinline__ f32x16 mfma32(bf16x8 a, bf16x8 b, f32x16 c) {
  return __builtin_amdgcn_mfma_f32_32x32x16_bf16(a, b, c, 0, 0, 0);
}

__global__ __launch_bounds__(512, 2)
void attn_fwd2(const __bf16* __restrict__ Q, const __bf16* __restrict__ Kk,
               const __bf16* __restrict__ Vt, __bf16* __restrict__ O) {
  __shared__ __bf16 Ks[2][64 * 64];   // [key][d], XOR-swizzled rows
  __shared__ __bf16 Vs[2][64 * 64];   // [d][key], XOR-swizzled rows

  const int tid = threadIdx.x;
  const int w = tid >> 6, lane = tid & 63;
  const int l31 = lane & 31, hi = lane >> 5;
  const int bh = blockIdx.x, b = bh >> 4, h = bh & 15;
  const int q0 = blockIdx.y * 256 + w * 32;

  // Q fragments (B-operand), prescaled by (1/8)*log2(e) for exp2-domain softmax
  bf16x8 qf[4];
  {
    const __bf16* qb = Q + (size_t)(b * SEQ + q0 + l31) * EMB + h * HDIM + hi * 8;
#pragma unroll
    for (int ks = 0; ks < 4; ++ks) {
      bf16x8 t = *(const bf16x8*)(qb + ks * 16);
#pragma unroll
      for (int j = 0; j < 8; ++j) t[j] = (__bf16)((float)t[j] * 0.1803368801111244f);
      qf[ks] = t;
    }
  }

  const int srow = w * 8 + (lane >> 3);
  const int sswz = ((lane & 7) * 16) ^ ((srow & 7) << 4);
  const char* kg = (const char*)(Kk + (size_t)(b * SEQ) * EMB + h * HDIM)
                   + (size_t)srow * (EMB * 2) + sswz;
  const char* vg = (const char*)(Vt + (size_t)((b * NHEAD + h) * HDIM) * SEQ)
                   + (size_t)srow * (SEQ * 2) + sswz;

  auto STAGE = [&](int bi, int t) {
    gload_lds16(kg + (size_t)t * (64 * EMB * 2), (char*)&Ks[bi][0] + w * 1024);
    gload_lds16(vg + (size_t)t * 128,            (char*)&Vs[bi][0] + w * 1024);
  };

  f32x16 oacc0 = {}, oacc1 = {};
  float mx = -1e30f, ls = 0.f;
  const int rswz = (l31 & 7) << 4;

  STAGE(0, 0);
  for (int t = 0; t < 32; ++t) {
    const int bi = t & 1;
    if (t < 31) {
      STAGE(bi ^ 1, t + 1);
      asm volatile("s_waitcnt vmcnt(2)" ::: "memory");
    } else {
      asm volatile("s_waitcnt vmcnt(0)" ::: "memory");
    }
    __builtin_amdgcn_s_barrier();
    __builtin_amdgcn_sched_barrier(0);

    // QK^T (swapped): S^T[key][q]
    f32x16 sc0 = {}, sc1 = {};
    const char* kb = (const char*)&Ks[bi][0];
#pragma unroll
    for (int ks = 0; ks < 4; ++ks) {
      const int o = (ks * 32 + hi * 16) ^ rswz;
      bf16x8 k0 = *(const bf16x8*)(kb + l31 * 128 + o);
      bf16x8 k1 = *(const bf16x8*)(kb + (l31 + 32) * 128 + o);
      sc0 = mfma32(k0, qf[ks], sc0);
      sc1 = mfma32(k1, qf[ks], sc1);
    }

    // online softmax in exp2 domain, per-lane row q
    float pm = sc0[0];
#pragma unroll
    for (int r = 1; r < 16; ++r) pm = fmaxf(pm, sc0[r]);
#pragma unroll
    for (int r = 0; r < 16; ++r) pm = fmaxf(pm, sc1[r]);
    pm = fmaxf(pm, __shfl_xor(pm, 32));
    const float mn = fmaxf(mx, pm);
    const float corr = __ocml_native_exp2_f32(mx - mn);
    mx = mn;
    float rs = 0.f;
#pragma unroll
    for (int r = 0; r < 16; ++r) { sc0[r] = __ocml_native_exp2_f32(sc0[r] - mn); rs += sc0[r]; }
#pragma unroll
    for (int r = 0; r < 16; ++r) { sc1[r] = __ocml_native_exp2_f32(sc1[r] - mn); rs += sc1[r]; }
    rs += __shfl_xor(rs, 32);
    ls = ls * corr + rs;
#pragma unroll
    for (int r = 0; r < 16; ++r) { oacc0[r] *= corr; oacc1[r] *= corr; }

    // P -> bf16 A-frags (P^T B-operand): pack pairs + lane^32 exchange
    union Fu { uint32_t w[4]; bf16x8 v; };
    auto pk = [](float a, float b) -> uint32_t {
      union { __bf16 h[2]; uint32_t u; } z;
      z.h[0] = (__bf16)a; z.h[1] = (__bf16)b; return z.u;
    };
    bf16x8 pa[4];
    {
      uint32_t A0 = pk(sc0[0], sc0[1]),  A1 = pk(sc0[2], sc0[3]);
      uint32_t B0 = pk(sc0[4], sc0[5]),  B1 = pk(sc0[6], sc0[7]);
      uint32_t C0 = pk(sc0[8], sc0[9]),  C1 = pk(sc0[10], sc0[11]);
      uint32_t D0 = pk(sc0[12], sc0[13]), D1 = pk(sc0[14], sc0[15]);
      uint32_t sA0 = __shfl_xor((int)A0, 32), sA1 = __shfl_xor((int)A1, 32);
      uint32_t sB0 = __shfl_xor((int)B0, 32), sB1 = __shfl_xor((int)B1, 32);
      uint32_t sC0 = __shfl_xor((int)C0, 32), sC1 = __shfl_xor((int)C1, 32);
      uint32_t sD0 = __shfl_xor((int)D0, 32), sD1 = __shfl_xor((int)D1, 32);
      Fu f0, f1;
      f0.w[0] = hi ? sB0 : A0;  f0.w[1] = hi ? sB1 : A1;
      f0.w[2] = hi ? B0 : sA0;  f0.w[3] = hi ? B1 : sA1;
      f1.w[0] = hi ? sD0 : C0;  f1.w[1] = hi ? sD1 : C1;
      f1.w[2] = hi ? D0 : sC0;  f1.w[3] = hi ? D1 : sC1;
      pa[0] = f0.v; pa[1] = f1.v;
      uint32_t E0 = pk(sc1[0], sc1[1]),  E1 = pk(sc1[2], sc1[3]);
      uint32_t F0 = pk(sc1[4], sc1[5]),  F1 = pk(sc1[6], sc1[7]);
      uint32_t G0 = pk(sc1[8], sc1[9]),  G1 = pk(sc1[10], sc1[11]);
      uint32_t H0 = pk(sc1[12], sc1[13]), H1 = pk(sc1[14], sc1[15]);
      uint32_t sE0 = __shfl_xor((int)E0, 32), sE1 = __shfl_xor((int)E1, 32);
      uint32_t sF0 = __shfl_xor((int)F0, 32), sF1 = __shfl_xor((int)F1, 32);
      uint32_t sG0 = __shfl_xor((int)G0, 32), sG1 = __shfl_xor((int)G1, 32);
      uint32_t sH0 = __shfl_xor((int)H0, 32), sH1 = __shfl_xor((int)H1, 32);
      Fu f2, f3;
      f2.w[0] = hi ? sF0 : E0;  f2.w[1] = hi ? sF1 : E1;
      f2.w[2] = hi ? F0 : sE0;  f2.w[3] = hi ? F1 : sE1;
      f3.w[0] = hi ? sH0 : G0;  f3.w[1] = hi ? sH1 : G1;
      f3.w[2] = hi ? H0 : sG0;  f3.w[3] = hi ? H1 : sG1;
      pa[2] = f2.v; pa[3] = f3.v;
    }

    // PV (swapped): O^T += Vt_tile . P^T
    const char* vb = (const char*)&Vs[bi][0];
#pragma unroll
    for (int ks = 0; ks < 4; ++ks) {
      const int o = (ks * 32 + hi * 16) ^ rswz;
      bf16x8 v0 = *(const bf16x8*)(vb + l31 * 128 + o);
      bf16x8 v1 = *(const bf16x8*)(vb + (l31 + 32) * 128 + o);
      oacc0 = mfma32(v0, pa[ks], oacc0);
      oacc1 = mfma32(v1, pa[ks], oacc1);
    }

    __builtin_amdgcn_s_barrier();
    __builtin_amdgcn_sched_barrier(0);
  }

  const float inv = 1.f / ls;
  __bf16* ob = O + (size_t)(b * SEQ + q0 + l31) * EMB + h * HDIM;
#pragma unroll
  for (int c = 0; c < 4; ++c) {
    union { ushort4 u; __bf16 x[4]; } o0, o1;
#pragma unroll
    for (int i = 0; i < 4; ++i) {
      o0.x[i] = (__bf16)(oacc0[4 * c + i] * inv);
      o1.x[i] = (__bf16)(oacc1[4 * c + i] * inv);
    }
    *(ushort4*)(ob + 8 * c + 4 * hi)      = o0.u;
    *(ushort4*)(ob + 32 + 8 * c + 4 * hi) = o1.u;
  }
}

// ---------------- launch ----------------
extern "C" void kernel_launch(void* const* d_in, const int* in_sizes, int n_in,
                              void* d_out, int out_size, void* d_ws, size_t ws_size,
                              hipStream_t stream) {
  const float* query = (const float*)d_in[0];
  const float* key   = (const float*)d_in[1];
  const float* value = (const float*)d_in[2];
  const float* Wq = (const float*)d_in[3]; const float* bq = (const float*)d_in[4];
  const float* Wk = (const float*)d_in[5]; const float* bk = (const float*)d_in[6];
  const float* Wv = (const float*)d_in[7]; const float* bv = (const float*)d_in[8];
  const float* Wo = (const float*)d_in[9]; const float* bo = (const float*)d_in[10];

  char* ws = (char*)d_ws;
  const size_t MB = 1u << 20;
  __bf16* Xb  = (__bf16*)(ws);             // 16 MB staging (also reused for attn out)
  __bf16* Qb  = (__bf16*)(ws + 16 * MB);
  __bf16* Kb  = (__bf16*)(ws + 32 * MB);
  __bf16* Vt  = (__bf16*)(ws + 48 * MB);
  __bf16* Wqb = (__bf16*)(ws + 64 * MB);
  __bf16* Wkb = (__bf16*)(ws + 66 * MB);
  __bf16* Wvb = (__bf16*)(ws + 68 * MB);
  __bf16* Wob = (__bf16*)(ws + 70 * MB);

  const int NE = BATCH * SEQ * EMB;
  const int NW = EMB * EMB;
  const int M = BATCH * SEQ;

  dim3 blk(256);
  dim3 gg(M / 256, EMB / 128);
  dim3 gblk(512);

  cvt_f32_bf16<<<dim3(NW / 4 / 256), blk, 0, stream>>>(Wq, Wqb, NW / 4);
  cvt_f32_bf16<<<dim3(NW / 4 / 256), blk, 0, stream>>>(Wk, Wkb, NW / 4);
  cvt_f32_bf16<<<dim3(NW / 4 / 256), blk, 0, stream>>>(Wv, Wvb, NW / 4);
  cvt_f32_bf16<<<dim3(NW / 4 / 256), blk, 0, stream>>>(Wo, Wob, NW / 4);

  cvt_f32_bf16<<<dim3(NE / 4 / 256), blk, 0, stream>>>(query, Xb, NE / 4);
  gemm3<EPI_BF16><<<gg, gblk, 0, stream>>>(Xb, Wqb, bq, Qb, M, EMB, EMB);
  cvt_f32_bf16<<<dim3(NE / 4 / 256), blk, 0, stream>>>(key, Xb, NE / 4);
  gemm3<EPI_BF16><<<gg, gblk, 0, stream>>>(Xb, Wkb, bk, Kb, M, EMB, EMB);
  cvt_f32_bf16<<<dim3(NE / 4 / 256), blk, 0, stream>>>(value, Xb, NE / 4);
  gemm3<EPI_VT><<<gg, gblk, 0, stream>>>(Xb, Wvb, bv, Vt, M, EMB, EMB);

  attn_fwd2<<<dim3(BATCH * NHEAD, SEQ / 256), gblk, 0, stream>>>(Qb, Kb, Vt, Xb);

  gemm3<EPI_F32><<<gg, gblk, 0, stream>>>(Xb, Wob, bo, d_out, M, EMB, EMB);
}

// Round 6
// 368.596 us; speedup vs baseline: 1.1222x; 1.0296x over previous
//
#include <hip/hip_runtime.h>
#include <hip/hip_bf16.h>
#include <stdint.h>

#define BATCH 4
#define SEQ   2048
#define EMB   1024
#define NHEAD 16
#define HDIM  64

typedef __bf16 bf16x8 __attribute__((ext_vector_type(8)));
typedef float  f32x4  __attribute__((ext_vector_type(4)));
typedef float  f32x16 __attribute__((ext_vector_type(16)));

extern "C" __device__ float __ocml_native_exp2_f32(float);  // raw v_exp_f32

__device__ __forceinline__ void gload_lds16(const void* g, void* l) {
  __builtin_amdgcn_global_load_lds((const uint32_t __attribute__((address_space(1)))*)g,
                                   (uint32_t __attribute__((address_space(3)))*)l, 16, 0, 0);
}

// ---------------- fused input casts: y selects (query,key,value) ----------------
__global__ __launch_bounds__(256) void cvt_inputs(const float* __restrict__ q,
                                                  const float* __restrict__ k,
                                                  const float* __restrict__ v,
                                                  __bf16* xq, __bf16* xk, __bf16* xv, int n4) {
  const float* in = (blockIdx.y == 0) ? q : (blockIdx.y == 1) ? k : v;
  __bf16* out     = (blockIdx.y == 0) ? xq : (blockIdx.y == 1) ? xk : xv;
  int i = blockIdx.x * 256 + threadIdx.x;
  if (i >= n4) return;
  float4 t = reinterpret_cast<const float4*>(in)[i];
  union { ushort4 u; __bf16 b[4]; } o;
  o.b[0] = (__bf16)t.x; o.b[1] = (__bf16)t.y;
  o.b[2] = (__bf16)t.z; o.b[3] = (__bf16)t.w;
  reinterpret_cast<ushort4*>(out)[i] = o.u;
}

// ---------------- fused weight casts: y selects (Wq,Wk,Wv,Wo) ----------------
__global__ __launch_bounds__(256) void cvt_weights(const float* w0, const float* w1,
                                                   const float* w2, const float* w3,
                                                   __bf16* o0, __bf16* o1,
                                                   __bf16* o2, __bf16* o3, int n4) {
  const float* in = (blockIdx.y == 0) ? w0 : (blockIdx.y == 1) ? w1 : (blockIdx.y == 2) ? w2 : w3;
  __bf16* out     = (blockIdx.y == 0) ? o0 : (blockIdx.y == 1) ? o1 : (blockIdx.y == 2) ? o2 : o3;
  int i = blockIdx.x * 256 + threadIdx.x;
  if (i >= n4) return;
  float4 t = reinterpret_cast<const float4*>(in)[i];
  union { ushort4 u; __bf16 b[4]; } o;
  o.b[0] = (__bf16)t.x; o.b[1] = (__bf16)t.y;
  o.b[2] = (__bf16)t.z; o.b[3] = (__bf16)t.w;
  reinterpret_cast<ushort4*>(out)[i] = o.u;
}

// ---------------- GEMM, m97 structure, batched over blockIdx.z ----------------
// C = A(8192x1024) * Bt(1024x1024)^T + bias. 128x128 tile, 256 thr (4 waves 2x2),
// BK=32, LDS 16KB, target 3 blocks/CU co-residency (the m102 833-TF regime).
enum { EPI_BF16 = 0, EPI_F32 = 1, EPI_VT = 2 };

struct GArg {
  const __bf16* A; const __bf16* Bt; const float* bias; void* C; int mode;
};

__global__ __launch_bounds__(256, 3)
void gemm97(GArg g0, GArg g1, GArg g2) {
  GArg g = g0;
  if (blockIdx.z == 1) g = g1;
  else if (blockIdx.z == 2) g = g2;

  __shared__ __bf16 As[128 * 32];
  __shared__ __bf16 Bs[128 * 32];
  const int tid  = threadIdx.x;
  const int wave = tid >> 6, lane = tid & 63;
  const int l4 = lane >> 4, l15 = lane & 15;
  const int row0 = blockIdx.x * 128, col0 = blockIdx.y * 128;
  const int wr = (wave >> 1) * 64, wc = (wave & 1) * 64;

  // staging map: LDS byte = wave*1024 + lane*16 (+4096) -> row-major [128][32] bf16
  const int srow = wave * 16 + (lane >> 2);
  const int scol = (lane & 3) * 8;

  f32x4 acc[4][4] = {};

  const __bf16* ga = g.A  + (size_t)(row0 + srow) * EMB + scol;
  const __bf16* gb = g.Bt + (size_t)(col0 + srow) * EMB + scol;
  char* lA = (char*)As + wave * 1024;
  char* lB = (char*)Bs + wave * 1024;

  for (int k0 = 0; k0 < EMB; k0 += 32) {
    __syncthreads();                     // prior tile's reads complete
    gload_lds16(ga + k0, lA);
    gload_lds16(ga + k0 + 64 * EMB, lA + 4096);
    gload_lds16(gb + k0, lB);
    gload_lds16(gb + k0 + 64 * EMB, lB + 4096);
    __syncthreads();                     // compiler drains vmcnt before barrier

    bf16x8 af[4], bfv[4];
#pragma unroll
    for (int m = 0; m < 4; ++m)
      af[m] = *(const bf16x8*)((const char*)As + (wr + m * 16 + l15) * 64 + l4 * 16);
#pragma unroll
    for (int n = 0; n < 4; ++n)
      bfv[n] = *(const bf16x8*)((const char*)Bs + (wc + n * 16 + l15) * 64 + l4 * 16);
#pragma unroll
    for (int m = 0; m < 4; ++m)
#pragma unroll
      for (int n = 0; n < 4; ++n)
        acc[m][n] = __builtin_amdgcn_mfma_f32_16x16x32_bf16(af[m], bfv[n], acc[m][n], 0, 0, 0);
  }

  // epilogue: D elem (row=l4*4+i, col=l15) per 16x16 frag; wave-uniform mode branch
#pragma unroll
  for (int m = 0; m < 4; ++m) {
    const int r = row0 + wr + m * 16 + l4 * 4;
#pragma unroll
    for (int n = 0; n < 4; ++n) {
      const int c  = col0 + wc + n * 16 + l15;
      const float bb = g.bias[c];
      if (g.mode == EPI_F32) {
        float* C = (float*)g.C;
#pragma unroll
        for (int i = 0; i < 4; ++i) C[(size_t)(r + i) * EMB + c] = acc[m][n][i] + bb;
      } else if (g.mode == EPI_BF16) {
        __bf16* C = (__bf16*)g.C;
#pragma unroll
        for (int i = 0; i < 4; ++i) C[(size_t)(r + i) * EMB + c] = (__bf16)(acc[m][n][i] + bb);
      } else {  // EPI_VT: write V^T as [b][h][d][s]
        const int b = r >> 11, s = r & (SEQ - 1);
        const int h = c >> 6, d = c & (HDIM - 1);
        union { ushort4 u; __bf16 x[4]; } o;
#pragma unroll
        for (int i = 0; i < 4; ++i) o.x[i] = (__bf16)(acc[m][n][i] + bb);
        *(ushort4*)((__bf16*)g.C + ((size_t)((b * NHEAD + h) * HDIM + d)) * SEQ + s) = o.u;
      }
    }
  }
}

// ---------------- flash attention: swapped-QK^T, 32x32 MFMA, defer-max ----------------
// grid (B*H=64, SEQ/256=8), 512 threads (8 waves x 32 q-rows).
__device__ __forceinline__ f32x16 mfma32(bf16x8 a, bf16x8 b, f32x16 c) {
  return __builtin_amdgcn_mfma_f32_32x32x16_bf16(a, b, c, 0, 0, 0);
}

__global__ __launch_bounds__(512, 2)
void attn_fwd2(const __bf16* __restrict__ Q, const __bf16* __restrict__ Kk,
               const __bf16* __restrict__ Vt, __bf16* __restrict__ O) {
  __shared__ __bf16 Ks[2][64 * 64];   // [key][d], XOR-swizzled rows
  __shared__ __bf16 Vs[2][64 * 64];   // [d][key], XOR-swizzled rows

  const int tid = threadIdx.x;
  const int w = tid >> 6, lane = tid & 63;
  const int l31 = lane & 31, hi = lane >> 5;
  const int bh = blockIdx.x, b = bh >> 4, h = bh & 15;
  const int q0 = blockIdx.y * 256 + w * 32;

  // Q fragments (B-operand), prescaled by (1/8)*log2(e) for exp2-domain softmax
  bf16x8 qf[4];
  {
    const __bf16* qb = Q + (size_t)(b * SEQ + q0 + l31) * EMB + h * HDIM + hi * 8;
#pragma unroll
    for (int ks = 0; ks < 4; ++ks) {
      bf16x8 t = *(const bf16x8*)(qb + ks * 16);
#pragma unroll
      for (int j = 0; j < 8; ++j) t[j] = (__bf16)((float)t[j] * 0.1803368801111244f);
      qf[ks] = t;
    }
  }

  const int srow = w * 8 + (lane >> 3);
  const int sswz = ((lane & 7) * 16) ^ ((srow & 7) << 4);
  const char* kg = (const char*)(Kk + (size_t)(b * SEQ) * EMB + h * HDIM)
                   + (size_t)srow * (EMB * 2) + sswz;
  const char* vg = (const char*)(Vt + (size_t)((b * NHEAD + h) * HDIM) * SEQ)
                   + (size_t)srow * (SEQ * 2) + sswz;

  auto STAGE = [&](int bi, int t) {
    gload_lds16(kg + (size_t)t * (64 * EMB * 2), (char*)&Ks[bi][0] + w * 1024);
    gload_lds16(vg + (size_t)t * 128,            (char*)&Vs[bi][0] + w * 1024);
  };

  f32x16 oacc0 = {}, oacc1 = {};
  float mx = -1e30f, ls = 0.f;
  const int rswz = (l31 & 7) << 4;

  STAGE(0, 0);
  for (int t = 0; t < 32; ++t) {
    const int bi = t & 1;
    if (t < 31) {
      STAGE(bi ^ 1, t + 1);
      asm volatile("s_waitcnt vmcnt(2)" ::: "memory");
    } else {
      asm volatile("s_waitcnt vmcnt(0)" ::: "memory");
    }
    __builtin_amdgcn_s_barrier();
    __builtin_amdgcn_sched_barrier(0);

    // QK^T (swapped): S^T[key][q]
    f32x16 sc0 = {}, sc1 = {};
    const char* kb = (const char*)&Ks[bi][0];
#pragma unroll
    for (int ks = 0; ks < 4; ++ks) {
      const int o = (ks * 32 + hi * 16) ^ rswz;
      bf16x8 k0 = *(const bf16x8*)(kb + l31 * 128 + o);
      bf16x8 k1 = *(const bf16x8*)(kb + (l31 + 32) * 128 + o);
      sc0 = mfma32(k0, qf[ks], sc0);
      sc1 = mfma32(k1, qf[ks], sc1);
    }

    // online softmax in exp2 domain, per-lane row q; T13 defer-max (THR=8)
    float pm = sc0[0];
#pragma unroll
    for (int r = 1; r < 16; ++r) pm = fmaxf(pm, sc0[r]);
#pragma unroll
    for (int r = 0; r < 16; ++r) pm = fmaxf(pm, sc1[r]);
    pm = fmaxf(pm, __shfl_xor(pm, 32));

    const bool resc = __any(pm > mx + 8.0f);
    float corr = 1.0f;
    if (resc) {
      const float mn = fmaxf(mx, pm);
      corr = __ocml_native_exp2_f32(mx - mn);
      mx = mn;
    }
    float rs = 0.f;
#pragma unroll
    for (int r = 0; r < 16; ++r) { sc0[r] = __ocml_native_exp2_f32(sc0[r] - mx); rs += sc0[r]; }
#pragma unroll
    for (int r = 0; r < 16; ++r) { sc1[r] = __ocml_native_exp2_f32(sc1[r] - mx); rs += sc1[r]; }
    rs += __shfl_xor(rs, 32);
    if (resc) {
      ls = ls * corr + rs;
#pragma unroll
      for (int r = 0; r < 16; ++r) { oacc0[r] *= corr; oacc1[r] *= corr; }
    } else {
      ls += rs;
    }

    // P -> bf16 A-frags (P^T B-operand): pack pairs + lane^32 exchange
    union Fu { uint32_t w[4]; bf16x8 v; };
    auto pk = [](float a, float b) -> uint32_t {
      union { __bf16 h[2]; uint32_t u; } z;
      z.h[0] = (__bf16)a; z.h[1] = (__bf16)b; return z.u;
    };
    bf16x8 pa[4];
    {
      uint32_t A0 = pk(sc0[0], sc0[1]),  A1 = pk(sc0[2], sc0[3]);
      uint32_t B0 = pk(sc0[4], sc0[5]),  B1 = pk(sc0[6], sc0[7]);
      uint32_t C0 = pk(sc0[8], sc0[9]),  C1 = pk(sc0[10], sc0[11]);
      uint32_t D0 = pk(sc0[12], sc0[13]), D1 = pk(sc0[14], sc0[15]);
      uint32_t sA0 = __shfl_xor((int)A0, 32), sA1 = __shfl_xor((int)A1, 32);
      uint32_t sB0 = __shfl_xor((int)B0, 32), sB1 = __shfl_xor((int)B1, 32);
      uint32_t sC0 = __shfl_xor((int)C0, 32), sC1 = __shfl_xor((int)C1, 32);
      uint32_t sD0 = __shfl_xor((int)D0, 32), sD1 = __shfl_xor((int)D1, 32);
      Fu f0, f1;
      f0.w[0] = hi ? sB0 : A0;  f0.w[1] = hi ? sB1 : A1;
      f0.w[2] = hi ? B0 : sA0;  f0.w[3] = hi ? B1 : sA1;
      f1.w[0] = hi ? sD0 : C0;  f1.w[1] = hi ? sD1 : C1;
      f1.w[2] = hi ? D0 : sC0;  f1.w[3] = hi ? D1 : sC1;
      pa[0] = f0.v; pa[1] = f1.v;
      uint32_t E0 = pk(sc1[0], sc1[1]),  E1 = pk(sc1[2], sc1[3]);
      uint32_t F0 = pk(sc1[4], sc1[5]),  F1 = pk(sc1[6], sc1[7]);
      uint32_t G0 = pk(sc1[8], sc1[9]),  G1 = pk(sc1[10], sc1[11]);
      uint32_t H0 = pk(sc1[12], sc1[13]), H1 = pk(sc1[14], sc1[15]);
      uint32_t sE0 = __shfl_xor((int)E0, 32), sE1 = __shfl_xor((int)E1, 32);
      uint32_t sF0 = __shfl_xor((int)F0, 32), sF1 = __shfl_xor((int)F1, 32);
      uint32_t sG0 = __shfl_xor((int)G0, 32), sG1 = __shfl_xor((int)G1, 32);
      uint32_t sH0 = __shfl_xor((int)H0, 32), sH1 = __shfl_xor((int)H1, 32);
      Fu f2, f3;
      f2.w[0] = hi ? sF0 : E0;  f2.w[1] = hi ? sF1 : E1;
      f2.w[2] = hi ? F0 : sE0;  f2.w[3] = hi ? F1 : sE1;
      f3.w[0] = hi ? sH0 : G0;  f3.w[1] = hi ? sH1 : G1;
      f3.w[2] = hi ? H0 : sG0;  f3.w[3] = hi ? H1 : sG1;
      pa[2] = f2.v; pa[3] = f3.v;
    }

    // PV (swapped): O^T += Vt_tile . P^T
    const char* vb = (const char*)&Vs[bi][0];
#pragma unroll
    for (int ks = 0; ks < 4; ++ks) {
      const int o = (ks * 32 + hi * 16) ^ rswz;
      bf16x8 v0 = *(const bf16x8*)(vb + l31 * 128 + o);
      bf16x8 v1 = *(const bf16x8*)(vb + (l31 + 32) * 128 + o);
      oacc0 = mfma32(v0, pa[ks], oacc0);
      oacc1 = mfma32(v1, pa[ks], oacc1);
    }

    __builtin_amdgcn_s_barrier();
    __builtin_amdgcn_sched_barrier(0);
  }

  const float inv = 1.f / ls;
  __bf16* ob = O + (size_t)(b * SEQ + q0 + l31) * EMB + h * HDIM;
#pragma unroll
  for (int c = 0; c < 4; ++c) {
    union { ushort4 u; __bf16 x[4]; } o0, o1;
#pragma unroll
    for (int i = 0; i < 4; ++i) {
      o0.x[i] = (__bf16)(oacc0[4 * c + i] * inv);
      o1.x[i] = (__bf16)(oacc1[4 * c + i] * inv);
    }
    *(ushort4*)(ob + 8 * c + 4 * hi)      = o0.u;
    *(ushort4*)(ob + 32 + 8 * c + 4 * hi) = o1.u;
  }
}

// ---------------- launch ----------------
extern "C" void kernel_launch(void* const* d_in, const int* in_sizes, int n_in,
                              void* d_out, int out_size, void* d_ws, size_t ws_size,
                              hipStream_t stream) {
  const float* query = (const float*)d_in[0];
  const float* key   = (const float*)d_in[1];
  const float* value = (const float*)d_in[2];
  const float* Wq = (const float*)d_in[3]; const float* bq = (const float*)d_in[4];
  const float* Wk = (const float*)d_in[5]; const float* bk = (const float*)d_in[6];
  const float* Wv = (const float*)d_in[7]; const float* bv = (const float*)d_in[8];
  const float* Wo = (const float*)d_in[9]; const float* bo = (const float*)d_in[10];

  char* ws = (char*)d_ws;
  const size_t MB = 1u << 20;
  // d_out (32MB f32) doubles as scratch for the two bf16 inputs consumed before
  // the final GEMM writes it: Xq @ d_out, Xk @ d_out+16MB.
  __bf16* Xq  = (__bf16*)d_out;
  __bf16* Xk  = (__bf16*)((char*)d_out + 16 * MB);
  __bf16* Xv  = (__bf16*)(ws);
  __bf16* Qb  = (__bf16*)(ws + 16 * MB);
  __bf16* Kb  = (__bf16*)(ws + 32 * MB);
  __bf16* Vt  = (__bf16*)(ws + 48 * MB);
  __bf16* Ao  = (__bf16*)(ws + 64 * MB);
  __bf16* Wqb = (__bf16*)(ws + 80 * MB);
  __bf16* Wkb = (__bf16*)(ws + 82 * MB);
  __bf16* Wvb = (__bf16*)(ws + 84 * MB);
  __bf16* Wob = (__bf16*)(ws + 86 * MB);

  const int NE = BATCH * SEQ * EMB;   // 8388608
  const int NW = EMB * EMB;           // 1048576
  const int M = BATCH * SEQ;

  cvt_weights<<<dim3(NW / 4 / 256, 4), 256, 0, stream>>>(Wq, Wk, Wv, Wo,
                                                         Wqb, Wkb, Wvb, Wob, NW / 4);
  cvt_inputs<<<dim3(NE / 4 / 256, 3), 256, 0, stream>>>(query, key, value,
                                                        Xq, Xk, Xv, NE / 4);

  GArg gq{Xq, Wqb, bq, Qb, EPI_BF16};
  GArg gk{Xk, Wkb, bk, Kb, EPI_BF16};
  GArg gv{Xv, Wvb, bv, Vt, EPI_VT};
  gemm97<<<dim3(M / 128, EMB / 128, 3), 256, 0, stream>>>(gq, gk, gv);

  attn_fwd2<<<dim3(BATCH * NHEAD, SEQ / 256), 512, 0, stream>>>(Qb, Kb, Vt, Ao);

  GArg go{Ao, Wob, bo, d_out, EPI_F32};
  gemm97<<<dim3(M / 128, EMB / 128, 1), 256, 0, stream>>>(go, go, go);
}